// Round 15
// baseline (365.905 us; speedup 1.0000x reference)
//
#include <hip/hip_runtime.h>
#include <cstdint>
#include <cstddef>

#define NN 100000
#define NE 1600000
#define DIM 256
#define NA 100352            // NN rounded up

// int-offset layout (compact, R13-proven):
#define OUTD_I  0
#define IND_I   NA
#define ROWP_I  (2*NA)
#define BSUM_I  (3*NA)
#define NSRC_I  (3*NA + 512)
#define NDST_I  (4*NA + 512)
#define CSR_I   (5*NA + 512)
#define HS_B    ((size_t)(CSR_I + NE) * 4)
#define WT_B    (HS_B + (size_t)NN*DIM*2)
#define RANK_B  (WT_B + (size_t)DIM*DIM*2)
#define WS_NEED (RANK_B + (size_t)NE*4)

typedef short bf16x8 __attribute__((ext_vector_type(8)));
typedef float f32x4 __attribute__((ext_vector_type(4)));
typedef unsigned short u16x4 __attribute__((ext_vector_type(4)));

__device__ __forceinline__ float bf2f(unsigned short u) {
    return __uint_as_float(((unsigned)u) << 16);
}
__device__ __forceinline__ unsigned short f2bf(float f) {
    unsigned u = __float_as_uint(f);
    u += 0x7FFF + ((u >> 16) & 1);   // round-to-nearest-even
    return (unsigned short)(u >> 16);
}

// ---- fused: 8-edge-unrolled histograms + ranks + h->bf16 convert -----------
// 8 edges/thread via int4 loads; 16 atomics issued back-to-back per thread
// before any rank store consumes a return -> ~4x more atomics in flight.
__global__ __launch_bounds__(256) void k_count_conv(
        const int* __restrict__ src, const int* __restrict__ dst,
        const float* __restrict__ h,
        int* __restrict__ outd, int* __restrict__ ind,
        int* __restrict__ rank, unsigned short* __restrict__ hs) {
    int gid = blockIdx.x * blockDim.x + threadIdx.x;
    if (gid < NE / 8) {
        int4 sa = ((const int4*)src)[gid * 2];
        int4 sb = ((const int4*)src)[gid * 2 + 1];
        int4 da = ((const int4*)dst)[gid * 2];
        int4 db = ((const int4*)dst)[gid * 2 + 1];
        atomicAdd(&outd[sa.x], 1);
        atomicAdd(&outd[sa.y], 1);
        atomicAdd(&outd[sa.z], 1);
        atomicAdd(&outd[sa.w], 1);
        atomicAdd(&outd[sb.x], 1);
        atomicAdd(&outd[sb.y], 1);
        atomicAdd(&outd[sb.z], 1);
        atomicAdd(&outd[sb.w], 1);
        int4 ra, rb;
        ra.x = atomicAdd(&ind[da.x], 1);
        ra.y = atomicAdd(&ind[da.y], 1);
        ra.z = atomicAdd(&ind[da.z], 1);
        ra.w = atomicAdd(&ind[da.w], 1);
        rb.x = atomicAdd(&ind[db.x], 1);
        rb.y = atomicAdd(&ind[db.y], 1);
        rb.z = atomicAdd(&ind[db.z], 1);
        rb.w = atomicAdd(&ind[db.w], 1);
        ((int4*)rank)[gid * 2] = ra;
        ((int4*)rank)[gid * 2 + 1] = rb;
    }
    // h -> raw bf16 (no dependency on histograms; overlaps the atomic pass)
    int gstride = gridDim.x * blockDim.x;
    for (int i = gid; i < NN * (DIM / 4); i += gstride) {
        float4 v = ((const float4*)h)[i];
        u16x4 o;
        o.x = f2bf(v.x);
        o.y = f2bf(v.y);
        o.z = f2bf(v.z);
        o.w = f2bf(v.w);
        ((u16x4*)hs)[i] = o;
    }
}

// ---- 3-kernel exclusive prefix scan of in_deg -> row_ptr -------------------
#define SCAN_NB 98   // ceil(NN/1024)

__global__ void k_scan1(const int* __restrict__ ind, int* __restrict__ rowp,
                        int* __restrict__ bsum) {
    __shared__ int tmp[1024];
    int t = threadIdx.x;
    int i = blockIdx.x * 1024 + t;
    int x = (i < NN) ? ind[i] : 0;
    tmp[t] = x;
    __syncthreads();
    for (int off = 1; off < 1024; off <<= 1) {
        int v = (t >= off) ? tmp[t - off] : 0;
        __syncthreads();
        tmp[t] += v;
        __syncthreads();
    }
    if (i < NN) rowp[i] = tmp[t] - x;           // exclusive within block
    if (t == 1023) bsum[blockIdx.x] = tmp[t];   // block total
}

__global__ void k_scan2(int* __restrict__ bsum) {
    __shared__ int tmp[128];
    int t = threadIdx.x;
    int x = (t < SCAN_NB) ? bsum[t] : 0;
    tmp[t] = x;
    __syncthreads();
    for (int off = 1; off < 128; off <<= 1) {
        int v = (t >= off) ? tmp[t - off] : 0;
        __syncthreads();
        tmp[t] += v;
        __syncthreads();
    }
    if (t < SCAN_NB) bsum[t] = tmp[t] - x;      // exclusive
}

// finalize rowp; emit normsrc/normdst compact f32 tables
__global__ void k_scan3(int* __restrict__ rowp, const int* __restrict__ bsum,
                        const int* __restrict__ outd, const int* __restrict__ ind,
                        float* __restrict__ normsrc, float* __restrict__ normdst) {
    int i = blockIdx.x * 1024 + threadIdx.x;
    if (i < NN) {
        rowp[i] += bsum[blockIdx.x];
        normsrc[i] = rsqrtf(fmaxf((float)outd[i], 1.0f));
        normdst[i] = rsqrtf(fmaxf((float)ind[i], 1.0f));
    }
    if (i == 0) rowp[NN] = NE;
}

// ---- streaming finish: CSR scatter + weight pack + hs *= normsrc -----------
// The premultiply removes the per-edge normsrc gather from k_aggemm
// (R14 evidence: that gather cost ~98 MB of HBM fetch).
__global__ __launch_bounds__(256) void k_scatter(
        const int* __restrict__ src, const int* __restrict__ dst,
        const int* __restrict__ rank, const int* __restrict__ rowp,
        const float* __restrict__ W, const float* __restrict__ normsrc,
        int* __restrict__ csr, unsigned short* __restrict__ wtp,
        unsigned short* __restrict__ hs) {
    int gid = blockIdx.x * blockDim.x + threadIdx.x;
    int gstride = gridDim.x * blockDim.x;
    // weight -> bf16 MFMA-fragment-packed (tiny)
    for (int p = gid; p < DIM * DIM; p += gstride) {
        int j = p & 7, l = (p >> 3) & 63, t = (p >> 9) & 15, ks = p >> 13;
        wtp[p] = f2bf(W[(ks * 32 + (l >> 4) * 8 + j) * DIM + t * 16 + (l & 15)]);
    }
    // CSR scatter: slot precomputed -> zero atomics
    for (int e = gid; e < NE; e += gstride) {
        csr[rowp[dst[e]] + rank[e]] = src[e];
    }
    // hs[node][:] *= normsrc[node]  (sequential 102 MB stream, BW headroom)
    for (int i = gid; i < NN * (DIM / 4); i += gstride) {
        int node = i >> 6;
        float s = normsrc[node];
        u16x4 v = ((u16x4*)hs)[i];
        v.x = f2bf(bf2f(v.x) * s);
        v.y = f2bf(bf2f(v.y) * s);
        v.z = f2bf(bf2f(v.z) * s);
        v.w = f2bf(bf2f(v.w) * s);
        ((u16x4*)hs)[i] = v;
    }
}

// ---- FUSED aggregate + GEMM + bias + ELU -----------------------------------
// readlane/SGPR-base gather structure (R13-proven); pure adds (hs premult).
__global__ __launch_bounds__(256) void k_aggemm(const unsigned short* __restrict__ hs,
                                                const int* __restrict__ csr,
                                                const int* __restrict__ rowp,
                                                const float* __restrict__ normdst,
                                                const unsigned short* __restrict__ wtp,
                                                const float* __restrict__ bias,
                                                float* __restrict__ out) {
    __shared__ short As[16][264];
    int wave = threadIdx.x >> 6;
    int lane = threadIdx.x & 63;
    int nb = blockIdx.x * 16;

    // ---- phase 1: aggregate 4 nodes per wave ----
    for (int i = 0; i < 4; ++i) {
        int r = wave * 4 + i;
        int node = nb + r;
        int e0 = rowp[node], e1 = rowp[node + 1];
        float a0 = 0.f, a1 = 0.f, a2 = 0.f, a3 = 0.f;
        for (int base = e0; base < e1; base += 64) {
            int n = e1 - base;
            if (n > 64) n = 64;
            int idx = base + lane;
            int csrv = (idx < e1) ? csr[idx] : 0;
            int j = 0;
            for (; j + 3 < n; j += 4) {
                int s0 = __builtin_amdgcn_readlane(csrv, j);
                int s1 = __builtin_amdgcn_readlane(csrv, j + 1);
                int s2 = __builtin_amdgcn_readlane(csrv, j + 2);
                int s3 = __builtin_amdgcn_readlane(csrv, j + 3);
                u16x4 u0 = ((const u16x4*)(hs + (size_t)s0 * DIM))[lane];
                u16x4 u1 = ((const u16x4*)(hs + (size_t)s1 * DIM))[lane];
                u16x4 u2 = ((const u16x4*)(hs + (size_t)s2 * DIM))[lane];
                u16x4 u3 = ((const u16x4*)(hs + (size_t)s3 * DIM))[lane];
                a0 += (bf2f(u0.x) + bf2f(u1.x)) + (bf2f(u2.x) + bf2f(u3.x));
                a1 += (bf2f(u0.y) + bf2f(u1.y)) + (bf2f(u2.y) + bf2f(u3.y));
                a2 += (bf2f(u0.z) + bf2f(u1.z)) + (bf2f(u2.z) + bf2f(u3.z));
                a3 += (bf2f(u0.w) + bf2f(u1.w)) + (bf2f(u2.w) + bf2f(u3.w));
            }
            for (; j < n; ++j) {
                int s0 = __builtin_amdgcn_readlane(csrv, j);
                u16x4 u = ((const u16x4*)(hs + (size_t)s0 * DIM))[lane];
                a0 += bf2f(u.x);
                a1 += bf2f(u.y);
                a2 += bf2f(u.z);
                a3 += bf2f(u.w);
            }
        }
        float nd = normdst[node];
        u16x4 o;
        o.x = f2bf(a0 * nd);
        o.y = f2bf(a1 * nd);
        o.z = f2bf(a2 * nd);
        o.w = f2bf(a3 * nd);
        *(u16x4*)&As[r][4 * lane] = o;   // linear across lanes: conflict-free
    }
    __syncthreads();

    // ---- phase 2: 16x256 GEMM quadrant per wave ----
    const short* B = (const short*)wtp + lane * 8;
    f32x4 acc[4];
#pragma unroll
    for (int tt = 0; tt < 4; ++tt) acc[tt] = (f32x4){0.f, 0.f, 0.f, 0.f};

    int fr = lane & 15;      // A-row / C-col fragment index
    int q  = lane >> 4;      // k-group / C-row group
    for (int ks = 0; ks < 8; ++ks) {
        bf16x8 a = *(const bf16x8*)&As[fr][ks * 32 + q * 8];
#pragma unroll
        for (int tt = 0; tt < 4; ++tt) {
            int t = wave * 4 + tt;
            bf16x8 b = *(const bf16x8*)(B + (size_t)(ks * 16 + t) * 512);
            acc[tt] = __builtin_amdgcn_mfma_f32_16x16x32_bf16(a, b, acc[tt], 0, 0, 0);
        }
    }

    // ---- epilogue: bias + ELU + store ----
    int rbase = nb + q * 4;
#pragma unroll
    for (int tt = 0; tt < 4; ++tt) {
        int col = wave * 64 + tt * 16 + fr;
        float bv = bias[col];
#pragma unroll
        for (int i = 0; i < 4; ++i) {
            float v = acc[tt][i] + bv;
            v = v > 0.f ? v : expm1f(v);
            __builtin_nontemporal_store(v, &out[(size_t)(rbase + i) * DIM + col]);
        }
    }
}

extern "C" void kernel_launch(void* const* d_in, const int* in_sizes, int n_in,
                              void* d_out, int out_size, void* d_ws, size_t ws_size,
                              hipStream_t stream) {
    const float* h    = (const float*)d_in[0];
    const float* W    = (const float*)d_in[1];
    const float* bias = (const float*)d_in[2];
    const int*   src  = (const int*)d_in[3];
    const int*   dst  = (const int*)d_in[4];
    float* out = (float*)d_out;

    if (ws_size < WS_NEED) return;  // insufficient scratch -> loud failure

    char* w = (char*)d_ws;
    int* base = (int*)w;
    int* outd = base + OUTD_I;
    int* ind  = base + IND_I;
    int* rowp = base + ROWP_I;
    int* bsum = base + BSUM_I;
    float* normsrc = (float*)(base + NSRC_I);
    float* normdst = (float*)(base + NDST_I);
    int* csr  = base + CSR_I;
    unsigned short* hs  = (unsigned short*)(w + HS_B);
    unsigned short* wtp = (unsigned short*)(w + WT_B);
    int* rank = (int*)(w + RANK_B);

    hipMemsetAsync(outd, 0, (size_t)2 * NA * sizeof(int), stream);  // outd+ind

    k_count_conv<<<(NE / 8 + 255) / 256, 256, 0, stream>>>(src, dst, h, outd, ind, rank, hs);
    k_scan1<<<SCAN_NB, 1024, 0, stream>>>(ind, rowp, bsum);
    k_scan2<<<1, 128, 0, stream>>>(bsum);
    k_scan3<<<SCAN_NB, 1024, 0, stream>>>(rowp, bsum, outd, ind, normsrc, normdst);
    k_scatter<<<2048, 256, 0, stream>>>(src, dst, rank, rowp, W, normsrc, csr, wtp, hs);
    k_aggemm<<<NN / 16, 256, 0, stream>>>(hs, csr, rowp, normdst, wtp, bias, out);
}

// Round 16
// 353.513 us; speedup vs baseline: 1.0351x; 1.0351x over previous
//
#include <hip/hip_runtime.h>
#include <cstdint>
#include <cstddef>

#define NN 100000
#define NE 1600000
#define DIM 256
#define NA 100352            // NN rounded up
#define NB 98                // coarse buckets of 1024 dst values
#define EPB 3125             // edges per scatter block (512 * 3125 = NE exactly)

// int-offset layout in ws:
#define OUTD_I   0                    // NA
#define COARSE_I NA                   // 128
#define BASE_I   (NA + 128)           // 128 (needs 99)
#define CURS_I   (NA + 256)           // 128
#define ROWP_I   (NA + 384)           // NA + 16
#define NDST_I   (2*NA + 400)         // NA (f32)
#define CSR_I    (3*NA + 400)         // NE
#define PAIR_I   (3*NA + 400 + NE)    // 2*NE (int2 pairs)
#define HS_B     ((size_t)(PAIR_I + 2*NE) * 4)
#define WT_B     (HS_B + (size_t)NN*DIM*2)
#define WS_NEED  (WT_B + (size_t)DIM*DIM*2)

typedef short bf16x8 __attribute__((ext_vector_type(8)));
typedef float f32x4 __attribute__((ext_vector_type(4)));
typedef unsigned short u16x4 __attribute__((ext_vector_type(4)));

__device__ __forceinline__ float bf2f(unsigned short u) {
    return __uint_as_float(((unsigned)u) << 16);
}
__device__ __forceinline__ unsigned short f2bf(float f) {
    unsigned u = __float_as_uint(f);
    u += 0x7FFF + ((u >> 16) & 1);   // round-to-nearest-even
    return (unsigned short)(u >> 16);
}

// ---- A: outd global histogram + coarse dst histogram (LDS) + h->bf16 -------
__global__ __launch_bounds__(256) void k_pre(
        const int* __restrict__ src, const int* __restrict__ dst,
        const float* __restrict__ h,
        int* __restrict__ outd, int* __restrict__ coarse,
        unsigned short* __restrict__ hs) {
    __shared__ int lh[NB];
    int tid = threadIdx.x;
    if (tid < NB) lh[tid] = 0;
    __syncthreads();
    int gid = blockIdx.x * blockDim.x + tid;
    int gstride = gridDim.x * blockDim.x;
    for (int e = gid; e < NE; e += gstride) {
        atomicAdd(&outd[src[e]], 1);          // the only bulk global atomics left
        atomicAdd(&lh[dst[e] >> 10], 1);      // LDS
    }
    // h -> raw bf16 (independent; overlaps the atomic pass)
    for (int i = gid; i < NN * (DIM / 4); i += gstride) {
        float4 v = ((const float4*)h)[i];
        u16x4 o;
        o.x = f2bf(v.x);
        o.y = f2bf(v.y);
        o.z = f2bf(v.z);
        o.w = f2bf(v.w);
        ((u16x4*)hs)[i] = o;
    }
    __syncthreads();
    if (tid < NB) atomicAdd(&coarse[tid], lh[tid]);
}

// ---- B: scan coarse -> bucket_base/cursor; rowp[NN]=NE ---------------------
__global__ void k_init(const int* __restrict__ coarse, int* __restrict__ base,
                       int* __restrict__ cursor, int* __restrict__ rowp) {
    __shared__ int tmp[128];
    int t = threadIdx.x;
    int x = (t < NB) ? coarse[t] : 0;
    tmp[t] = x;
    __syncthreads();
    for (int off = 1; off < 128; off <<= 1) {
        int v = (t >= off) ? tmp[t - off] : 0;
        __syncthreads();
        tmp[t] += v;
        __syncthreads();
    }
    if (t < NB) {
        int excl = tmp[t] - x;
        base[t] = excl;
        cursor[t] = excl;
    }
    if (t == 0) {
        base[NB] = NE;
        rowp[NN] = NE;
    }
}

// ---- D: scatter pairs into coarse buckets (LDS ranks) + premult + wt pack --
__global__ __launch_bounds__(256) void k_scatter2(
        const int* __restrict__ src, const int* __restrict__ dst,
        const int* __restrict__ outd, const float* __restrict__ W,
        int* __restrict__ cursor, int* __restrict__ pairs,
        unsigned short* __restrict__ hs, unsigned short* __restrict__ wtp) {
    __shared__ int lh[NB];
    __shared__ int cur[NB];
    int tid = threadIdx.x;
    int e0 = blockIdx.x * EPB, e1 = e0 + EPB;   // exact partition
    if (tid < NB) lh[tid] = 0;
    __syncthreads();
    for (int e = e0 + tid; e < e1; e += 256)
        atomicAdd(&lh[dst[e] >> 10], 1);
    __syncthreads();
    if (tid < NB) cur[tid] = atomicAdd(&cursor[tid], lh[tid]);  // 98/block global
    __syncthreads();
    for (int e = e0 + tid; e < e1; e += 256) {
        int d = dst[e], s = src[e];
        int pos = atomicAdd(&cur[d >> 10], 1);   // LDS returning
        ((int2*)pairs)[pos] = make_int2(d, s);
    }
    // weight pack (tiny)
    int gid = blockIdx.x * 256 + tid;
    if (gid < DIM * DIM) {
        int p = gid;
        int j = p & 7, l = (p >> 3) & 63, t = (p >> 9) & 15, ks = p >> 13;
        wtp[p] = f2bf(W[(ks * 32 + (l >> 4) * 8 + j) * DIM + t * 16 + (l & 15)]);
    }
    // hs *= normsrc (outd complete after k_pre); 153 MB stream
    int gstride = gridDim.x * 256;
    for (int i = gid; i < NN * (DIM / 4); i += gstride) {
        int node = i >> 6;
        float s = rsqrtf(fmaxf((float)outd[node], 1.0f));
        u16x4 v = ((u16x4*)hs)[i];
        v.x = f2bf(bf2f(v.x) * s);
        v.y = f2bf(bf2f(v.y) * s);
        v.z = f2bf(bf2f(v.z) * s);
        v.w = f2bf(bf2f(v.w) * s);
        ((u16x4*)hs)[i] = v;
    }
}

// ---- E: per-bucket fine histogram + rowp + normdst + csr (all LDS-local) ---
__global__ __launch_bounds__(256) void k_fine(
        const int* __restrict__ pairs, const int* __restrict__ base,
        int* __restrict__ rowp, float* __restrict__ normdst,
        int* __restrict__ csr) {
    __shared__ int fine[1024];
    __shared__ int excl[1024];
    __shared__ int part[256];
    int tid = threadIdx.x;
    int bin = blockIdx.x;
    int lo = bin << 10;
    int ebase = base[bin], eend = base[bin + 1];
#pragma unroll
    for (int k = 0; k < 4; ++k) fine[tid * 4 + k] = 0;
    __syncthreads();
    for (int e = ebase + tid; e < eend; e += 256) {
        int d = ((const int2*)pairs)[e].x;
        atomicAdd(&fine[d - lo], 1);
    }
    __syncthreads();
    // exclusive scan of 1024 counts: 4/thread serial + 256-wide block scan
    int c0 = fine[tid * 4], c1 = fine[tid * 4 + 1];
    int c2 = fine[tid * 4 + 2], c3 = fine[tid * 4 + 3];
    int psum = c0 + c1 + c2 + c3;
    part[tid] = psum;
    __syncthreads();
    for (int off = 1; off < 256; off <<= 1) {
        int v = (tid >= off) ? part[tid - off] : 0;
        __syncthreads();
        part[tid] += v;
        __syncthreads();
    }
    int eb = part[tid] - psum;   // exclusive over this thread's 4 bins
    excl[tid * 4] = eb;
    excl[tid * 4 + 1] = eb + c0;
    excl[tid * 4 + 2] = eb + c0 + c1;
    excl[tid * 4 + 3] = eb + c0 + c1 + c2;
    // rowp + normdst for this bucket's nodes
#pragma unroll
    for (int k = 0; k < 4; ++k) {
        int j = tid * 4 + k;
        int node = lo + j;
        if (node < NN) {
            rowp[node] = ebase + excl[j];
            normdst[node] = rsqrtf(fmaxf((float)fine[j], 1.0f));
        }
    }
    __syncthreads();
    // rank + csr write (LDS returning atomics; row order arbitrary)
    for (int e = ebase + tid; e < eend; e += 256) {
        int2 p = ((const int2*)pairs)[e];
        int r = atomicAdd(&excl[p.x - lo], 1);
        csr[ebase + r] = p.y;
    }
}

// ---- F: FUSED aggregate + GEMM + bias + ELU (R15-verbatim, proven) ---------
__global__ __launch_bounds__(256) void k_aggemm(const unsigned short* __restrict__ hs,
                                                const int* __restrict__ csr,
                                                const int* __restrict__ rowp,
                                                const float* __restrict__ normdst,
                                                const unsigned short* __restrict__ wtp,
                                                const float* __restrict__ bias,
                                                float* __restrict__ out) {
    __shared__ short As[16][264];
    int wave = threadIdx.x >> 6;
    int lane = threadIdx.x & 63;
    int nb = blockIdx.x * 16;

    for (int i = 0; i < 4; ++i) {
        int r = wave * 4 + i;
        int node = nb + r;
        int e0 = rowp[node], e1 = rowp[node + 1];
        float a0 = 0.f, a1 = 0.f, a2 = 0.f, a3 = 0.f;
        for (int base = e0; base < e1; base += 64) {
            int n = e1 - base;
            if (n > 64) n = 64;
            int idx = base + lane;
            int csrv = (idx < e1) ? csr[idx] : 0;
            int j = 0;
            for (; j + 3 < n; j += 4) {
                int s0 = __builtin_amdgcn_readlane(csrv, j);
                int s1 = __builtin_amdgcn_readlane(csrv, j + 1);
                int s2 = __builtin_amdgcn_readlane(csrv, j + 2);
                int s3 = __builtin_amdgcn_readlane(csrv, j + 3);
                u16x4 u0 = ((const u16x4*)(hs + (size_t)s0 * DIM))[lane];
                u16x4 u1 = ((const u16x4*)(hs + (size_t)s1 * DIM))[lane];
                u16x4 u2 = ((const u16x4*)(hs + (size_t)s2 * DIM))[lane];
                u16x4 u3 = ((const u16x4*)(hs + (size_t)s3 * DIM))[lane];
                a0 += (bf2f(u0.x) + bf2f(u1.x)) + (bf2f(u2.x) + bf2f(u3.x));
                a1 += (bf2f(u0.y) + bf2f(u1.y)) + (bf2f(u2.y) + bf2f(u3.y));
                a2 += (bf2f(u0.z) + bf2f(u1.z)) + (bf2f(u2.z) + bf2f(u3.z));
                a3 += (bf2f(u0.w) + bf2f(u1.w)) + (bf2f(u2.w) + bf2f(u3.w));
            }
            for (; j < n; ++j) {
                int s0 = __builtin_amdgcn_readlane(csrv, j);
                u16x4 u = ((const u16x4*)(hs + (size_t)s0 * DIM))[lane];
                a0 += bf2f(u.x);
                a1 += bf2f(u.y);
                a2 += bf2f(u.z);
                a3 += bf2f(u.w);
            }
        }
        float nd = normdst[node];
        u16x4 o;
        o.x = f2bf(a0 * nd);
        o.y = f2bf(a1 * nd);
        o.z = f2bf(a2 * nd);
        o.w = f2bf(a3 * nd);
        *(u16x4*)&As[r][4 * lane] = o;
    }
    __syncthreads();

    const short* B = (const short*)wtp + lane * 8;
    f32x4 acc[4];
#pragma unroll
    for (int tt = 0; tt < 4; ++tt) acc[tt] = (f32x4){0.f, 0.f, 0.f, 0.f};

    int fr = lane & 15;
    int q  = lane >> 4;
    for (int ks = 0; ks < 8; ++ks) {
        bf16x8 a = *(const bf16x8*)&As[fr][ks * 32 + q * 8];
#pragma unroll
        for (int tt = 0; tt < 4; ++tt) {
            int t = wave * 4 + tt;
            bf16x8 b = *(const bf16x8*)(B + (size_t)(ks * 16 + t) * 512);
            acc[tt] = __builtin_amdgcn_mfma_f32_16x16x32_bf16(a, b, acc[tt], 0, 0, 0);
        }
    }

    int rbase = nb + q * 4;
#pragma unroll
    for (int tt = 0; tt < 4; ++tt) {
        int col = wave * 64 + tt * 16 + fr;
        float bv = bias[col];
#pragma unroll
        for (int i = 0; i < 4; ++i) {
            float v = acc[tt][i] + bv;
            v = v > 0.f ? v : expm1f(v);
            __builtin_nontemporal_store(v, &out[(size_t)(rbase + i) * DIM + col]);
        }
    }
}

extern "C" void kernel_launch(void* const* d_in, const int* in_sizes, int n_in,
                              void* d_out, int out_size, void* d_ws, size_t ws_size,
                              hipStream_t stream) {
    const float* h    = (const float*)d_in[0];
    const float* W    = (const float*)d_in[1];
    const float* bias = (const float*)d_in[2];
    const int*   src  = (const int*)d_in[3];
    const int*   dst  = (const int*)d_in[4];
    float* out = (float*)d_out;

    if (ws_size < WS_NEED) return;  // insufficient scratch -> loud failure

    char* w = (char*)d_ws;
    int* base_i = (int*)w;
    int* outd   = base_i + OUTD_I;
    int* coarse = base_i + COARSE_I;
    int* bbase  = base_i + BASE_I;
    int* cursor = base_i + CURS_I;
    int* rowp   = base_i + ROWP_I;
    float* normdst = (float*)(base_i + NDST_I);
    int* csr    = base_i + CSR_I;
    int* pairs  = base_i + PAIR_I;
    unsigned short* hs  = (unsigned short*)(w + HS_B);
    unsigned short* wtp = (unsigned short*)(w + WT_B);

    // zero outd + coarse (contiguous)
    hipMemsetAsync(outd, 0, (size_t)(NA + 128) * sizeof(int), stream);

    k_pre<<<2048, 256, 0, stream>>>(src, dst, h, outd, coarse, hs);
    k_init<<<1, 128, 0, stream>>>(coarse, bbase, cursor, rowp);
    k_scatter2<<<512, 256, 0, stream>>>(src, dst, outd, W, cursor, pairs, hs, wtp);
    k_fine<<<NB, 256, 0, stream>>>(pairs, bbase, rowp, normdst, csr);
    k_aggemm<<<NN / 16, 256, 0, stream>>>(hs, csr, rowp, normdst, wtp, bias, out);
}

// Round 17
// 282.650 us; speedup vs baseline: 1.2946x; 1.2507x over previous
//
#include <hip/hip_runtime.h>
#include <cstdint>
#include <cstddef>

#define NN 100000
#define NE 1600000
#define DIM 256
#define NA 100352            // NN rounded up
#define NB 98                // buckets of 1024 node ids
#define SCB 512              // scatter blocks
#define EPB (NE / SCB)       // 3125 edges per scatter block (exact)

// int-offset layout in ws:
#define CD_I   0                      // coarseD[128]
#define CS_I   128                    // coarseS[128]
#define BD_I   256                    // baseD[129]
#define BS_I   392                    // baseS[129]
#define GCD_I  528                    // global cursorD[128]
#define GCS_I  656                    // global cursorS[128]
#define ROWP_I 800                    // rowp[NA+16]
#define NDST_I (800 + NA + 16)        // normdst f32[NA]
#define NSRC_I (800 + 2*NA + 16)      // normsrc f32[NA]
#define CSR_I  (800 + 3*NA + 16)      // csr[NE]
#define SRCV_I (CSR_I + NE)           // srcv[NE]
#define PAIR_I (SRCV_I + NE)          // pairs int2[NE]
#define HS_B   ((size_t)(PAIR_I + 2*NE) * 4)
#define WT_B   (HS_B + (size_t)NN*DIM*2)
#define WS_NEED (WT_B + (size_t)DIM*DIM*2)

typedef short bf16x8 __attribute__((ext_vector_type(8)));
typedef float f32x4 __attribute__((ext_vector_type(4)));
typedef unsigned short u16x4 __attribute__((ext_vector_type(4)));

__device__ __forceinline__ float bf2f(unsigned short u) {
    return __uint_as_float(((unsigned)u) << 16);
}
__device__ __forceinline__ unsigned short f2bf(float f) {
    unsigned u = __float_as_uint(f);
    u += 0x7FFF + ((u >> 16) & 1);   // round-to-nearest-even
    return (unsigned short)(u >> 16);
}

// ---- A: coarse LDS histograms (src & dst) + h->bf16 convert ----------------
// ZERO bulk global atomics: only 2*98 flush-adds per block (512 blocks).
__global__ __launch_bounds__(256) void k_pre(
        const int* __restrict__ src, const int* __restrict__ dst,
        const float* __restrict__ h,
        int* __restrict__ coarseD, int* __restrict__ coarseS,
        unsigned short* __restrict__ hs) {
    __shared__ int lhd[NB], lhs[NB];
    int tid = threadIdx.x;
    if (tid < NB) { lhd[tid] = 0; lhs[tid] = 0; }
    __syncthreads();
    int gid = blockIdx.x * blockDim.x + tid;
    int gstride = gridDim.x * blockDim.x;
    for (int e = gid; e < NE; e += gstride) {
        atomicAdd(&lhs[src[e] >> 10], 1);   // LDS
        atomicAdd(&lhd[dst[e] >> 10], 1);   // LDS
    }
    for (int i = gid; i < NN * (DIM / 4); i += gstride) {
        float4 v = ((const float4*)h)[i];
        u16x4 o;
        o.x = f2bf(v.x);
        o.y = f2bf(v.y);
        o.z = f2bf(v.z);
        o.w = f2bf(v.w);
        ((u16x4*)hs)[i] = o;
    }
    __syncthreads();
    if (tid < NB) {
        atomicAdd(&coarseD[tid], lhd[tid]);
        atomicAdd(&coarseS[tid], lhs[tid]);
    }
}

// ---- B: scan both coarse histograms -> bases/cursors -----------------------
__global__ void k_init(const int* __restrict__ coarseD, const int* __restrict__ coarseS,
                       int* __restrict__ baseD, int* __restrict__ baseS,
                       int* __restrict__ gcurD, int* __restrict__ gcurS,
                       int* __restrict__ rowp) {
    __shared__ int tmp[128];
    int t = threadIdx.x;
    // dst side
    int x = (t < NB) ? coarseD[t] : 0;
    tmp[t] = x;
    __syncthreads();
    for (int off = 1; off < 128; off <<= 1) {
        int v = (t >= off) ? tmp[t - off] : 0;
        __syncthreads();
        tmp[t] += v;
        __syncthreads();
    }
    if (t < NB) { int e = tmp[t] - x; baseD[t] = e; gcurD[t] = e; }
    __syncthreads();
    // src side
    int y = (t < NB) ? coarseS[t] : 0;
    tmp[t] = y;
    __syncthreads();
    for (int off = 1; off < 128; off <<= 1) {
        int v = (t >= off) ? tmp[t - off] : 0;
        __syncthreads();
        tmp[t] += v;
        __syncthreads();
    }
    if (t < NB) { int e = tmp[t] - y; baseS[t] = e; gcurS[t] = e; }
    if (t == 0) {
        baseD[NB] = NE;
        baseS[NB] = NE;
        rowp[NN] = NE;
    }
}

// ---- C: scatter (d,s) by dst bucket + s by src bucket + weight pack --------
__global__ __launch_bounds__(256) void k_scatter2(
        const int* __restrict__ src, const int* __restrict__ dst,
        const float* __restrict__ W,
        int* __restrict__ gcurD, int* __restrict__ gcurS,
        int* __restrict__ pairs, int* __restrict__ srcv,
        unsigned short* __restrict__ wtp) {
    __shared__ int lhd[NB], lhs[NB], curd[NB], curs[NB];
    int tid = threadIdx.x;
    int e0 = blockIdx.x * EPB, e1 = e0 + EPB;   // exact partition
    if (tid < NB) { lhd[tid] = 0; lhs[tid] = 0; }
    __syncthreads();
    for (int e = e0 + tid; e < e1; e += 256) {
        atomicAdd(&lhd[dst[e] >> 10], 1);
        atomicAdd(&lhs[src[e] >> 10], 1);
    }
    __syncthreads();
    if (tid < NB) {
        curd[tid] = atomicAdd(&gcurD[tid], lhd[tid]);   // 98/block global
        curs[tid] = atomicAdd(&gcurS[tid], lhs[tid]);
    }
    __syncthreads();
    for (int e = e0 + tid; e < e1; e += 256) {
        int d = dst[e], s = src[e];
        int pos = atomicAdd(&curd[d >> 10], 1);    // LDS returning
        ((int2*)pairs)[pos] = make_int2(d, s);
        int pos2 = atomicAdd(&curs[s >> 10], 1);
        srcv[pos2] = s;
    }
    // weight pack (tiny)
    int gid = blockIdx.x * 256 + tid;
    if (gid < DIM * DIM) {
        int p = gid;
        int j = p & 7, l = (p >> 3) & 63, t = (p >> 9) & 15, ks = p >> 13;
        wtp[p] = f2bf(W[(ks * 32 + (l >> 4) * 8 + j) * DIM + t * 16 + (l & 15)]);
    }
}

// ---- D: per-bucket fine pass, all LDS-local --------------------------------
// blocks [0,NB):   dst side -> in-deg, rowp, normdst, csr ranks
// blocks [NB,2NB): src side -> out-deg -> normsrc
__global__ __launch_bounds__(256) void k_fine(
        const int* __restrict__ pairs, const int* __restrict__ srcv,
        const int* __restrict__ baseD, const int* __restrict__ baseS,
        int* __restrict__ rowp, float* __restrict__ normdst,
        float* __restrict__ normsrc, int* __restrict__ csr) {
    __shared__ int fine[1024];
    __shared__ int excl[1024];
    __shared__ int part[256];
    int tid = threadIdx.x;
    if (blockIdx.x >= NB) {                       // ---- src side ----
        int bin = blockIdx.x - NB;
        int lo = bin << 10;
        int ebase = baseS[bin], eend = baseS[bin + 1];
#pragma unroll
        for (int k = 0; k < 4; ++k) fine[tid * 4 + k] = 0;
        __syncthreads();
        for (int e = ebase + tid; e < eend; e += 256)
            atomicAdd(&fine[srcv[e] - lo], 1);
        __syncthreads();
#pragma unroll
        for (int k = 0; k < 4; ++k) {
            int j = tid * 4 + k;
            int node = lo + j;
            if (node < NN)
                normsrc[node] = rsqrtf(fmaxf((float)fine[j], 1.0f));
        }
        return;
    }
    // ---- dst side (R16-proven) ----
    int bin = blockIdx.x;
    int lo = bin << 10;
    int ebase = baseD[bin], eend = baseD[bin + 1];
#pragma unroll
    for (int k = 0; k < 4; ++k) fine[tid * 4 + k] = 0;
    __syncthreads();
    for (int e = ebase + tid; e < eend; e += 256) {
        int d = ((const int2*)pairs)[e].x;
        atomicAdd(&fine[d - lo], 1);
    }
    __syncthreads();
    int c0 = fine[tid * 4], c1 = fine[tid * 4 + 1];
    int c2 = fine[tid * 4 + 2], c3 = fine[tid * 4 + 3];
    int psum = c0 + c1 + c2 + c3;
    part[tid] = psum;
    __syncthreads();
    for (int off = 1; off < 256; off <<= 1) {
        int v = (tid >= off) ? part[tid - off] : 0;
        __syncthreads();
        part[tid] += v;
        __syncthreads();
    }
    int eb = part[tid] - psum;
    excl[tid * 4] = eb;
    excl[tid * 4 + 1] = eb + c0;
    excl[tid * 4 + 2] = eb + c0 + c1;
    excl[tid * 4 + 3] = eb + c0 + c1 + c2;
#pragma unroll
    for (int k = 0; k < 4; ++k) {
        int j = tid * 4 + k;
        int node = lo + j;
        if (node < NN) {
            rowp[node] = ebase + excl[j];
            normdst[node] = rsqrtf(fmaxf((float)fine[j], 1.0f));
        }
    }
    __syncthreads();
    for (int e = ebase + tid; e < eend; e += 256) {
        int2 p = ((const int2*)pairs)[e];
        int r = atomicAdd(&excl[p.x - lo], 1);
        csr[ebase + r] = p.y;
    }
}

// ---- E: FUSED aggregate + GEMM + bias + ELU (R14-refcheck'd inner loop) ----
__global__ __launch_bounds__(256) void k_aggemm(const unsigned short* __restrict__ hs,
                                                const int* __restrict__ csr,
                                                const int* __restrict__ rowp,
                                                const float* __restrict__ normdst,
                                                const float* __restrict__ normsrc,
                                                const unsigned short* __restrict__ wtp,
                                                const float* __restrict__ bias,
                                                float* __restrict__ out) {
    __shared__ short As[16][264];
    int wave = threadIdx.x >> 6;
    int lane = threadIdx.x & 63;
    int nb = blockIdx.x * 16;

    for (int i = 0; i < 4; ++i) {
        int r = wave * 4 + i;
        int node = nb + r;
        int e0 = rowp[node], e1 = rowp[node + 1];
        float a0 = 0.f, a1 = 0.f, a2 = 0.f, a3 = 0.f;
        for (int base = e0; base < e1; base += 64) {
            int n = e1 - base;
            if (n > 64) n = 64;
            int idx = base + lane;
            int csrv = (idx < e1) ? csr[idx] : 0;
            int j = 0;
            for (; j + 3 < n; j += 4) {
                int s0 = __builtin_amdgcn_readlane(csrv, j);
                int s1 = __builtin_amdgcn_readlane(csrv, j + 1);
                int s2 = __builtin_amdgcn_readlane(csrv, j + 2);
                int s3 = __builtin_amdgcn_readlane(csrv, j + 3);
                float n0 = normsrc[s0], n1 = normsrc[s1];
                float n2 = normsrc[s2], n3 = normsrc[s3];
                u16x4 u0 = ((const u16x4*)(hs + (size_t)s0 * DIM))[lane];
                u16x4 u1 = ((const u16x4*)(hs + (size_t)s1 * DIM))[lane];
                u16x4 u2 = ((const u16x4*)(hs + (size_t)s2 * DIM))[lane];
                u16x4 u3 = ((const u16x4*)(hs + (size_t)s3 * DIM))[lane];
                a0 = fmaf(bf2f(u0.x), n0, fmaf(bf2f(u1.x), n1,
                     fmaf(bf2f(u2.x), n2, fmaf(bf2f(u3.x), n3, a0))));
                a1 = fmaf(bf2f(u0.y), n0, fmaf(bf2f(u1.y), n1,
                     fmaf(bf2f(u2.y), n2, fmaf(bf2f(u3.y), n3, a1))));
                a2 = fmaf(bf2f(u0.z), n0, fmaf(bf2f(u1.z), n1,
                     fmaf(bf2f(u2.z), n2, fmaf(bf2f(u3.z), n3, a2))));
                a3 = fmaf(bf2f(u0.w), n0, fmaf(bf2f(u1.w), n1,
                     fmaf(bf2f(u2.w), n2, fmaf(bf2f(u3.w), n3, a3))));
            }
            for (; j < n; ++j) {
                int s0 = __builtin_amdgcn_readlane(csrv, j);
                float n0 = normsrc[s0];
                u16x4 u = ((const u16x4*)(hs + (size_t)s0 * DIM))[lane];
                a0 = fmaf(bf2f(u.x), n0, a0);
                a1 = fmaf(bf2f(u.y), n0, a1);
                a2 = fmaf(bf2f(u.z), n0, a2);
                a3 = fmaf(bf2f(u.w), n0, a3);
            }
        }
        float nd = normdst[node];
        u16x4 o;
        o.x = f2bf(a0 * nd);
        o.y = f2bf(a1 * nd);
        o.z = f2bf(a2 * nd);
        o.w = f2bf(a3 * nd);
        *(u16x4*)&As[r][4 * lane] = o;
    }
    __syncthreads();

    const short* B = (const short*)wtp + lane * 8;
    f32x4 acc[4];
#pragma unroll
    for (int tt = 0; tt < 4; ++tt) acc[tt] = (f32x4){0.f, 0.f, 0.f, 0.f};

    int fr = lane & 15;
    int q  = lane >> 4;
    for (int ks = 0; ks < 8; ++ks) {
        bf16x8 a = *(const bf16x8*)&As[fr][ks * 32 + q * 8];
#pragma unroll
        for (int tt = 0; tt < 4; ++tt) {
            int t = wave * 4 + tt;
            bf16x8 b = *(const bf16x8*)(B + (size_t)(ks * 16 + t) * 512);
            acc[tt] = __builtin_amdgcn_mfma_f32_16x16x32_bf16(a, b, acc[tt], 0, 0, 0);
        }
    }

    int rbase = nb + q * 4;
#pragma unroll
    for (int tt = 0; tt < 4; ++tt) {
        int col = wave * 64 + tt * 16 + fr;
        float bv = bias[col];
#pragma unroll
        for (int i = 0; i < 4; ++i) {
            float v = acc[tt][i] + bv;
            v = v > 0.f ? v : expm1f(v);
            __builtin_nontemporal_store(v, &out[(size_t)(rbase + i) * DIM + col]);
        }
    }
}

extern "C" void kernel_launch(void* const* d_in, const int* in_sizes, int n_in,
                              void* d_out, int out_size, void* d_ws, size_t ws_size,
                              hipStream_t stream) {
    const float* h    = (const float*)d_in[0];
    const float* W    = (const float*)d_in[1];
    const float* bias = (const float*)d_in[2];
    const int*   src  = (const int*)d_in[3];
    const int*   dst  = (const int*)d_in[4];
    float* out = (float*)d_out;

    if (ws_size < WS_NEED) return;  // insufficient scratch -> loud failure

    char* w = (char*)d_ws;
    int* bi = (int*)w;
    int* coarseD = bi + CD_I;
    int* coarseS = bi + CS_I;
    int* baseD   = bi + BD_I;
    int* baseS   = bi + BS_I;
    int* gcurD   = bi + GCD_I;
    int* gcurS   = bi + GCS_I;
    int* rowp    = bi + ROWP_I;
    float* normdst = (float*)(bi + NDST_I);
    float* normsrc = (float*)(bi + NSRC_I);
    int* csr     = bi + CSR_I;
    int* srcv    = bi + SRCV_I;
    int* pairs   = bi + PAIR_I;
    unsigned short* hs  = (unsigned short*)(w + HS_B);
    unsigned short* wtp = (unsigned short*)(w + WT_B);

    hipMemsetAsync(coarseD, 0, 256 * sizeof(int), stream);  // coarseD+coarseS

    k_pre<<<512, 256, 0, stream>>>(src, dst, h, coarseD, coarseS, hs);
    k_init<<<1, 128, 0, stream>>>(coarseD, coarseS, baseD, baseS, gcurD, gcurS, rowp);
    k_scatter2<<<SCB, 256, 0, stream>>>(src, dst, W, gcurD, gcurS, pairs, srcv, wtp);
    k_fine<<<2 * NB, 256, 0, stream>>>(pairs, srcv, baseD, baseS, rowp, normdst, normsrc, csr);
    k_aggemm<<<NN / 16, 256, 0, stream>>>(hs, csr, rowp, normdst, normsrc, wtp, bias, out);
}